// Round 1
// baseline (207660.742 us; speedup 1.0000x reference)
//
#include <hip/hip_runtime.h>

// RNNDetector: 2-layer LSTM (H=64) over T=262144 steps, batch 1, + 16-wide linear head.
// Strictly sequential scan -> single workgroup (1 CU), both layers software-pipelined:
//   superstep s: layer0 computes h0(s), layer1 computes h1(s-1), head emits out(s-2).
// Weights live in VGPRs (per-thread rows); h state transits through LDS with 2 barriers/step.

constexpr int T  = 262144;
constexpr int H  = 64;
constexpr int NSTEP = T + 2;

typedef float v4 __attribute__((ext_vector_type(4)));

__device__ __forceinline__ float fast_rcp(float x) { return __builtin_amdgcn_rcpf(x); }

// sigmoid / tanh via fast exp+rcp; clamp keeps (1-e)/(1+e) away from inf/inf.
__device__ __forceinline__ float act_sigmoid(float x) {
  return fast_rcp(1.f + __expf(-x));
}
__device__ __forceinline__ float act_tanh(float x) {
  float xc = fminf(fmaxf(x, -15.f), 15.f);
  float e  = __expf(-2.f * xc);
  return (1.f - e) * fast_rcp(1.f + e);
}

// 64-length dot of a register-resident row against an LDS vector (broadcast reads).
__device__ __forceinline__ float dot64(const float (&w)[64], const float* hs) {
  v4 acc = {0.f, 0.f, 0.f, 0.f};
  const v4* h4 = (const v4*)hs;
  #pragma unroll
  for (int r = 0; r < 16; ++r) {
    v4 hv = h4[r];
    v4 wv = { w[4*r+0], w[4*r+1], w[4*r+2], w[4*r+3] };
    acc += hv * wv;   // -ffp-contract: v_fma / v_pk_fma_f32
  }
  return (acc.x + acc.y) + (acc.z + acc.w);
}

__global__ __launch_bounds__(512, 2) void rnn_fused(
    const float* __restrict__ y,
    const float* __restrict__ Wih0, const float* __restrict__ Whh0,
    const float* __restrict__ bih0, const float* __restrict__ bhh0,
    const float* __restrict__ Wih1, const float* __restrict__ Whh1,
    const float* __restrict__ bih1, const float* __restrict__ bhh1,
    const float* __restrict__ Wlin, const float* __restrict__ blin,
    float* __restrict__ out)
{
  const int tid   = threadIdx.x;
  const bool isL1 = tid >= 256;      // waves 4-7: layer-1 gates
  const int  j    = tid & 255;       // gate row (0..255), PyTorch order i,f,g,o
  const int  gate = j >> 6;          // 0=i 1=f 2=g 3=o  (wave-uniform)
  const int  e    = j & 63;          // element index
  const bool isTanh = (gate == 2);

  __shared__ __align__(16) float h0s[H];
  __shared__ __align__(16) float h1s[H];
  __shared__ float g0t[H * 5];       // stride 5: conflict-free writes, easy i/f/g/o gather
  __shared__ float g1t[H * 5];

  float A[64];                       // L0: Whh0 row | L1: Wih1 row
  float B[64];                       // L1: Whh1 row | wave1: B[0..15] = Wlin K-slice
  float bb = 0.f, wi0 = 0.f, blin_r = 0.f;

  if (!isL1) {
    const v4* src = (const v4*)(Whh0 + j * 64);
    #pragma unroll
    for (int r = 0; r < 16; ++r) {
      v4 t = src[r];
      A[4*r+0]=t.x; A[4*r+1]=t.y; A[4*r+2]=t.z; A[4*r+3]=t.w;
    }
    wi0 = Wih0[j];                   // W_ih0 is [256,1]
    bb  = bih0[j] + bhh0[j];
    if (tid >= 64 && tid < 128) {    // wave 1 doubles as the output head
      int lane = tid - 64, m = lane & 15, part = lane >> 4;
      #pragma unroll
      for (int q = 0; q < 16; ++q) B[q] = Wlin[m * 64 + part * 16 + q];
      blin_r = blin[m];
    }
  } else {
    const v4* sa = (const v4*)(Wih1 + j * 64);
    const v4* sb = (const v4*)(Whh1 + j * 64);
    #pragma unroll
    for (int r = 0; r < 16; ++r) {
      v4 ta = sa[r];
      A[4*r+0]=ta.x; A[4*r+1]=ta.y; A[4*r+2]=ta.z; A[4*r+3]=ta.w;
      v4 tb = sb[r];
      B[4*r+0]=tb.x; B[4*r+1]=tb.y; B[4*r+2]=tb.z; B[4*r+3]=tb.w;
    }
    bb = bih1[j] + bhh1[j];
  }

  float c = 0.f;                     // c0 for tid<64, c1 for tid in [256,320)
  if (tid < 64) { h0s[tid] = 0.f; h1s[tid] = 0.f; }
  float y_cur = isL1 ? 0.f : y[0];
  __syncthreads();

  #pragma unroll 1
  for (int s = 0; s < NSTEP; ++s) {
    // ---------------- phase 1: gate dots + head ----------------
    if (!isL1) {
      if (s < T) {                   // layer0 computes h0(s)
        float y_nxt = (s + 1 < T) ? y[s + 1] : 0.f;   // prefetch, hidden by dot
        float pre = dot64(A, h0s) + fmaf(y_cur, wi0, bb);
        g0t[e * 5 + gate] = isTanh ? act_tanh(pre) : act_sigmoid(pre);
        y_cur = y_nxt;
      }
      if (tid >= 64 && tid < 128 && s >= 2) {   // head emits out(s-2) from h1 in LDS
        int lane = tid - 64, m = lane & 15, part = lane >> 4;
        const float* hp = h1s + part * 16;
        v4 acc = {0.f,0.f,0.f,0.f};
        #pragma unroll
        for (int r = 0; r < 4; ++r) {
          v4 hv = ((const v4*)hp)[r];
          v4 wv = { B[4*r+0], B[4*r+1], B[4*r+2], B[4*r+3] };
          acc += hv * wv;
        }
        float partial = (acc.x + acc.y) + (acc.z + acc.w);
        partial += __shfl_xor(partial, 16);
        partial += __shfl_xor(partial, 32);
        if (part == 0) out[(s - 2) * 16 + m] = partial + blin_r;
      }
    } else {
      if (s >= 1 && s <= T) {        // layer1 computes h1(s-1); x_t = h0(s-1) in LDS
        float pre = dot64(A, h0s) + dot64(B, h1s) + bb;
        g1t[e * 5 + gate] = isTanh ? act_tanh(pre) : act_sigmoid(pre);
      }
    }
    __syncthreads();
    // ---------------- phase 2: c/h updates ----------------
    if (tid < 64 && s < T) {
      float gi = g0t[tid*5+0], gf = g0t[tid*5+1], gg = g0t[tid*5+2], go = g0t[tid*5+3];
      c = fmaf(gf, c, gi * gg);
      h0s[tid] = go * act_tanh(c);
    }
    if (tid >= 256 && tid < 320 && s >= 1 && s <= T) {
      int k = tid - 256;
      float gi = g1t[k*5+0], gf = g1t[k*5+1], gg = g1t[k*5+2], go = g1t[k*5+3];
      c = fmaf(gf, c, gi * gg);
      h1s[k] = go * act_tanh(c);
    }
    __syncthreads();
  }
}

extern "C" void kernel_launch(void* const* d_in, const int* in_sizes, int n_in,
                              void* d_out, int out_size, void* d_ws, size_t ws_size,
                              hipStream_t stream) {
  const float* y    = (const float*)d_in[0];
  const float* Wih0 = (const float*)d_in[1];
  const float* Whh0 = (const float*)d_in[2];
  const float* bih0 = (const float*)d_in[3];
  const float* bhh0 = (const float*)d_in[4];
  const float* Wih1 = (const float*)d_in[5];
  const float* Whh1 = (const float*)d_in[6];
  const float* bih1 = (const float*)d_in[7];
  const float* bhh1 = (const float*)d_in[8];
  const float* Wlin = (const float*)d_in[9];
  const float* blin = (const float*)d_in[10];

  rnn_fused<<<dim3(1), dim3(512), 0, stream>>>(
      y, Wih0, Whh0, bih0, bhh0, Wih1, Whh1, bih1, bhh1, Wlin, blin,
      (float*)d_out);
}

// Round 2
// 203294.873 us; speedup vs baseline: 1.0215x; 1.0215x over previous
//
#include <hip/hip_runtime.h>

// RNNDetector: 2-layer LSTM (H=64) over T=262144 steps + 16-wide linear head.
// Strictly sequential -> 1 workgroup (1 CU), 512 threads:
//   threads   0-255 : layer-0 gates. thread t -> element e=t>>2, gate r=t&3
//                     (row j = r*64+e of W). Each element's 4 gates live in one
//                     lane-quad -> gate exchange via __shfl_xor, NO LDS/barrier.
//                     Also computes the linear head (in-wave 16-lane reduce).
//   threads 256-511 : layer-1 gates, same mapping, two 64-dots (Wih1, Whh1).
// Weights in NAMED v4 registers (round-1 float[64] arrays were demoted to
// scratch: VGPR_Count=84 proved it). h state double-buffered in LDS,
// ONE barrier per superstep. Pipeline: step s computes h0(s), h1(s-1), out(s-2).

constexpr int T = 262144;

typedef float v4 __attribute__((ext_vector_type(4)));

__device__ __forceinline__ float rcp_f(float x) { return __builtin_amdgcn_rcpf(x); }

#define DECL_LOAD16(V, ptr)                                        \
  const v4* V##_p = (const v4*)(ptr);                              \
  v4 V##0 = V##_p[0],  V##1 = V##_p[1],  V##2 = V##_p[2],  V##3 = V##_p[3],   \
     V##4 = V##_p[4],  V##5 = V##_p[5],  V##6 = V##_p[6],  V##7 = V##_p[7],   \
     V##8 = V##_p[8],  V##9 = V##_p[9],  V##10 = V##_p[10], V##11 = V##_p[11],\
     V##12 = V##_p[12], V##13 = V##_p[13], V##14 = V##_p[14], V##15 = V##_p[15]

// 64-dot of register row V against LDS vector H4 (broadcast reads), 2 fma chains.
#define DOT64(res, V, H4) {                                        \
  v4 _x = V##0 * (H4)[0];                                          \
  v4 _y = V##1 * (H4)[1];                                          \
  _x += V##2  * (H4)[2];   _y += V##3  * (H4)[3];                  \
  _x += V##4  * (H4)[4];   _y += V##5  * (H4)[5];                  \
  _x += V##6  * (H4)[6];   _y += V##7  * (H4)[7];                  \
  _x += V##8  * (H4)[8];   _y += V##9  * (H4)[9];                  \
  _x += V##10 * (H4)[10];  _y += V##11 * (H4)[11];                 \
  _x += V##12 * (H4)[12];  _y += V##13 * (H4)[13];                 \
  _x += V##14 * (H4)[14];  _y += V##15 * (H4)[15];                 \
  v4 _s = _x + _y;                                                 \
  res = (_s.x + _s.y) + (_s.z + _s.w); }

__global__ __launch_bounds__(512, 2) void rnn_fused(
    const float* __restrict__ y,
    const float* __restrict__ Wih0, const float* __restrict__ Whh0,
    const float* __restrict__ bih0, const float* __restrict__ bhh0,
    const float* __restrict__ Wih1, const float* __restrict__ Whh1,
    const float* __restrict__ bih1, const float* __restrict__ bhh1,
    const float* __restrict__ Wlin, const float* __restrict__ blin,
    float* __restrict__ out)
{
  const int tid  = threadIdx.x;
  const bool isL1 = tid >= 256;
  const int t8  = tid & 255;
  const int r   = t8 & 3;        // gate: 0=i 1=f 2=g 3=o  (quad lane)
  const int e   = t8 >> 2;       // element 0..63
  const int j   = r * 64 + e;    // weight row (PyTorch gate order)

  __shared__ __align__(16) float h0b[2][64];
  __shared__ __align__(16) float h1b[2][64];

  // ---- weights into NAMED registers (no arrays -> no scratch demotion) ----
  const float* rowA = isL1 ? (Wih1 + j * 64) : (Whh0 + j * 64);
  const float* rowB = isL1 ? (Whh1 + j * 64) : (Whh0 + j * 64);  // dummy for L0
  DECL_LOAD16(A, rowA);
  DECL_LOAD16(B, rowB);

  const float bb  = isL1 ? (bih1[j] + bhh1[j]) : (bih0[j] + bhh0[j]);
  const float wi0 = isL1 ? 0.f : Wih0[j];

  // head constants (L0 threads only): m = output idx, 4-wide K slice
  const int hm = t8 >> 4;
  const int hk = (t8 & 15) << 2;
  v4 WL = {0.f, 0.f, 0.f, 0.f};
  float bl = 0.f;
  if (!isL1) {
    WL = *(const v4*)(Wlin + hm * 64 + hk);
    if ((t8 & 15) == 0) bl = blin[hm];
  }

  // per-lane activation constants
  const float kmul = (r == 2) ? 2.f : 1.f;   // tanh gate uses exp(-2x)
  const bool  isG  = (r == 2);
  const bool  oddl = (r & 1);
  const bool  hiq  = (r & 2);

  float c = 0.f;                 // cell state (consistent across the quad)
  if (tid < 64) { h0b[0][tid] = 0.f; h0b[1][tid] = 0.f;
                  h1b[0][tid] = 0.f; h1b[1][tid] = 0.f; }
  float y_cur = isL1 ? 0.f : y[0];
  __syncthreads();

  #pragma unroll 2
  for (int s = 0; s < T + 2; ++s) {
    const int cur = s & 1;
    const float* h0c = h0b[cur];
    const float* h1c = h1b[cur];
    float* h0n = h0b[cur ^ 1];
    float* h1n = h1b[cur ^ 1];

    if (!isL1) {
      // ---- layer 0: h0(s) ----
      if (s < T) {
        float y_nxt = (s + 1 < T) ? y[s + 1] : 0.f;   // prefetch (broadcast)
        const v4* h4 = (const v4*)h0c;
        float d; DOT64(d, A, h4);
        float pre = d + fmaf(y_cur, wi0, bb);
        // activation: sigmoid(x)=1/(1+e^-x); tanh(x)=(1-e^-2x)/(1+e^-2x)
        float z  = fminf(fmaxf(pre * kmul, -30.f), 30.f);
        float ex = __expf(-z);
        float a  = (isG ? (1.f - ex) : 1.f) * rcp_f(1.f + ex);
        // quad exchange: lane r has {a = gate r, b2 = gate r^2}
        float b2 = __shfl_xor(a, 2);
        float fo = hiq ? b2 : a;            // odd lanes: the f gate
        float m1 = oddl ? fo : a;           // even: i (or g)
        float m2 = oddl ? c  : b2;          // even: g (or i)
        float p  = m1 * m2;                 // even: i*g, odd: f*c
        float cn = p + __shfl_xor(p, 1);    // c_new in all lanes
        c = cn;
        float zt = fminf(fmaxf(cn, -15.f), 15.f);
        float e2 = __expf(-2.f * zt);
        float th = (1.f - e2) * rcp_f(1.f + e2);
        float oo = hiq ? a : b2;            // odd lanes: the o gate
        float h  = oo * th;
        if (r == 3) h0n[e] = h;
        y_cur = y_nxt;
      }
      // ---- head: out(s-2) from h1[cur] ----
      if (s >= 2) {
        const v4 hh = *(const v4*)(h1c + hk);
        v4 tt = WL * hh;
        float p = (tt.x + tt.y) + (tt.z + tt.w);
        p += __shfl_xor(p, 1);
        p += __shfl_xor(p, 2);
        p += __shfl_xor(p, 4);
        p += __shfl_xor(p, 8);
        if ((t8 & 15) == 0) out[(s - 2) * 16 + hm] = p + bl;
      }
    } else {
      // ---- layer 1: h1(s-1) ----
      if (s >= 1 && s <= T) {
        const v4* h4a = (const v4*)h0c;   // x_t = h0(s-1)
        const v4* h4b = (const v4*)h1c;   // h1(s-2)
        float da, db;
        DOT64(da, A, h4a);
        DOT64(db, B, h4b);
        float pre = da + db + bb;
        float z  = fminf(fmaxf(pre * kmul, -30.f), 30.f);
        float ex = __expf(-z);
        float a  = (isG ? (1.f - ex) : 1.f) * rcp_f(1.f + ex);
        float b2 = __shfl_xor(a, 2);
        float fo = hiq ? b2 : a;
        float m1 = oddl ? fo : a;
        float m2 = oddl ? c  : b2;
        float p  = m1 * m2;
        float cn = p + __shfl_xor(p, 1);
        c = cn;
        float zt = fminf(fmaxf(cn, -15.f), 15.f);
        float e2 = __expf(-2.f * zt);
        float th = (1.f - e2) * rcp_f(1.f + e2);
        float oo = hiq ? a : b2;
        float h  = oo * th;
        if (r == 3) h1n[e] = h;
      }
    }
    __syncthreads();   // ONE barrier per superstep (ping-pong h buffers)
  }
}

extern "C" void kernel_launch(void* const* d_in, const int* in_sizes, int n_in,
                              void* d_out, int out_size, void* d_ws, size_t ws_size,
                              hipStream_t stream) {
  const float* y    = (const float*)d_in[0];
  const float* Wih0 = (const float*)d_in[1];
  const float* Whh0 = (const float*)d_in[2];
  const float* bih0 = (const float*)d_in[3];
  const float* bhh0 = (const float*)d_in[4];
  const float* Wih1 = (const float*)d_in[5];
  const float* Whh1 = (const float*)d_in[6];
  const float* bih1 = (const float*)d_in[7];
  const float* bhh1 = (const float*)d_in[8];
  const float* Wlin = (const float*)d_in[9];
  const float* blin = (const float*)d_in[10];

  rnn_fused<<<dim3(1), dim3(512), 0, stream>>>(
      y, Wih0, Whh0, bih0, bhh0, Wih1, Whh1, bih1, bhh1, Wlin, blin,
      (float*)d_out);
}